// Round 7
// baseline (262.698 us; speedup 1.0000x reference)
//
#include <hip/hip_runtime.h>
#include <hip/hip_bf16.h>

#define BS 4
#define NQ 6000
#define NV 13294
#define NH 8
#define HD 32
#define EMB 256
#define MV (BS * NV)  // 53176
#define MQ (BS * NQ)  // 24000

typedef __attribute__((ext_vector_type(8))) short short8;
typedef __attribute__((ext_vector_type(4))) float floatx4;

__device__ __constant__ float LVL_DIM[4] = {100.f, 50.f, 25.f, 13.f};

__device__ inline unsigned short bf16bits(float f) {
  __hip_bfloat16 h = __float2bfloat16(f);
  return *reinterpret_cast<unsigned short*>(&h);
}
__device__ inline float bflo(unsigned int u) { return __uint_as_float(u << 16); }
__device__ inline float bfhi(unsigned int u) { return __uint_as_float(u & 0xffff0000u); }

__device__ inline short8 cvt8(float4 a, float4 b) {
  short8 r;
  r[0] = (short)bf16bits(a.x);
  r[1] = (short)bf16bits(a.y);
  r[2] = (short)bf16bits(a.z);
  r[3] = (short)bf16bits(a.w);
  r[4] = (short)bf16bits(b.x);
  r[5] = (short)bf16bits(b.y);
  r[6] = (short)bf16bits(b.z);
  r[7] = (short)bf16bits(b.w);
  return r;
}

// ---------------------------------------------------------------------------
// Weight transpose + bf16 convert: Wt[n][k] = bf16(W[k][n]).
// ---------------------------------------------------------------------------
__global__ __launch_bounds__(256) void wtrans_kernel(
    const float* __restrict__ W_val, const float* __restrict__ W_off,
    const float* __restrict__ W_attn, const float* __restrict__ W_out,
    unsigned short* __restrict__ Wt_val, unsigned short* __restrict__ Wt_qcat,
    unsigned short* __restrict__ Wt_out) {
  const int b = blockIdx.x, k = threadIdx.x;
  if (b < 256) {
    Wt_val[b * EMB + k] = bf16bits(W_val[k * 256 + b]);
  } else if (b < 640) {
    const int n = b - 256;
    float v = (n < 256) ? W_off[k * 256 + n] : W_attn[k * 128 + (n - 256)];
    Wt_qcat[n * EMB + k] = bf16bits(v);
  } else {
    const int n = b - 640;
    Wt_out[n * EMB + k] = bf16bits(W_out[k * 256 + n]);
  }
}

// ---------------------------------------------------------------------------
// B-resident GEMM: B tile (128 cols x K=256) lives in LDS for the whole
// kernel (64 KB, XOR-swizzled 8-short groups: pos = g ^ (n&31) -> 2-way
// bank aliasing on reads = free). A is loaded straight from global into
// MFMA fragment order (no LDS, no K-loop barriers), bf16-converted in-reg,
// 2-iteration register prefetch.
// ---------------------------------------------------------------------------
__device__ inline void loadB_tile(const unsigned short* __restrict__ B, int NB,
                                  int n0, unsigned short* ldsB, int tid) {
  const int n = tid >> 1, h = tid & 1;
  const int row = n0 + n;
  unsigned short* dst = ldsB + n * 256;
  if (row < NB) {
    const unsigned short* src = B + (size_t)row * EMB;
#pragma unroll
    for (int j = 0; j < 16; ++j) {
      const int g = h * 16 + j;
      *(uint4*)(dst + (((g ^ (n & 31)) << 3))) =
          *(const uint4*)(src + (g << 3));
    }
  } else {
    uint4 z = make_uint4(0, 0, 0, 0);
#pragma unroll
    for (int j = 0; j < 16; ++j) {
      const int g = h * 16 + j;
      *(uint4*)(dst + (((g ^ (n & 31)) << 3))) = z;
    }
  }
}

// A fp32 (value/query): per iter 8 dwordx4 loads + cvt, 4 ds_read_b128 for B.
__device__ inline void gemm_bres_f32A(const float* __restrict__ A, int M,
                                      int m0, const unsigned short* ldsB,
                                      int wm, int wn, int lane,
                                      floatx4 acc[4][4]) {
  const int quad = lane >> 4, ml = lane & 15;
  const float* aptr[4];
#pragma unroll
  for (int mt = 0; mt < 4; ++mt) {
    int row = m0 + wm * 64 + mt * 16 + ml;
    row = min(row, M - 1);
    aptr[mt] = A + (size_t)row * EMB + quad * 8;
  }
  float4 fa[2][8];
#pragma unroll
  for (int p = 0; p < 2; ++p)
#pragma unroll
    for (int mt = 0; mt < 4; ++mt) {
      fa[p][2 * mt] = *(const float4*)(aptr[mt] + p * 32);
      fa[p][2 * mt + 1] = *(const float4*)(aptr[mt] + p * 32 + 4);
    }
#pragma unroll
  for (int k = 0; k < 8; ++k) {
    short8 af[4];
#pragma unroll
    for (int mt = 0; mt < 4; ++mt)
      af[mt] = cvt8(fa[k & 1][2 * mt], fa[k & 1][2 * mt + 1]);
    if (k + 2 < 8) {
#pragma unroll
      for (int mt = 0; mt < 4; ++mt) {
        fa[k & 1][2 * mt] = *(const float4*)(aptr[mt] + (k + 2) * 32);
        fa[k & 1][2 * mt + 1] = *(const float4*)(aptr[mt] + (k + 2) * 32 + 4);
      }
    }
    short8 bf[4];
#pragma unroll
    for (int nt = 0; nt < 4; ++nt) {
      const int n = wn * 64 + nt * 16 + ml;
      bf[nt] = *(const short8*)(ldsB + n * 256 +
                                ((((k * 4 + quad) ^ (n & 31)) << 3)));
    }
#pragma unroll
    for (int mt = 0; mt < 4; ++mt)
#pragma unroll
      for (int nt = 0; nt < 4; ++nt)
        acc[mt][nt] = __builtin_amdgcn_mfma_f32_16x16x32_bf16(
            af[mt], bf[nt], acc[mt][nt], 0, 0, 0);
  }
}

// A bf16 (sampled): per iter 4 dwordx4 loads, no conversion.
__device__ inline void gemm_bres_bf16A(const unsigned short* __restrict__ A,
                                       int M, int m0,
                                       const unsigned short* ldsB, int wm,
                                       int wn, int lane, floatx4 acc[4][4]) {
  const int quad = lane >> 4, ml = lane & 15;
  const unsigned short* aptr[4];
#pragma unroll
  for (int mt = 0; mt < 4; ++mt) {
    int row = m0 + wm * 64 + mt * 16 + ml;
    row = min(row, M - 1);
    aptr[mt] = A + (size_t)row * EMB + quad * 8;
  }
  short8 fa[2][4];
#pragma unroll
  for (int p = 0; p < 2; ++p)
#pragma unroll
    for (int mt = 0; mt < 4; ++mt)
      fa[p][mt] = *(const short8*)(aptr[mt] + p * 32);
#pragma unroll
  for (int k = 0; k < 8; ++k) {
    short8 af[4];
#pragma unroll
    for (int mt = 0; mt < 4; ++mt) af[mt] = fa[k & 1][mt];
    if (k + 2 < 8) {
#pragma unroll
      for (int mt = 0; mt < 4; ++mt)
        fa[k & 1][mt] = *(const short8*)(aptr[mt] + (k + 2) * 32);
    }
    short8 bf[4];
#pragma unroll
    for (int nt = 0; nt < 4; ++nt) {
      const int n = wn * 64 + nt * 16 + ml;
      bf[nt] = *(const short8*)(ldsB + n * 256 +
                                ((((k * 4 + quad) ^ (n & 31)) << 3)));
    }
#pragma unroll
    for (int mt = 0; mt < 4; ++mt)
#pragma unroll
      for (int nt = 0; nt < 4; ++nt)
        acc[mt][nt] = __builtin_amdgcn_mfma_f32_16x16x32_bf16(
            af[mt], bf[nt], acc[mt][nt], 0, 0, 0);
  }
}

// ---------------------------------------------------------------------------
// Fused K1+K2: blocks [0,832): value proj; [832,1408): offset/attn proj.
// ---------------------------------------------------------------------------
__global__ __launch_bounds__(256, 2) void vqproj_kernel(
    const float* __restrict__ value, const unsigned short* __restrict__ Wt_val,
    const float* __restrict__ b_val, unsigned short* __restrict__ vbh,
    const float* __restrict__ query, const unsigned short* __restrict__ Wt_qcat,
    const float* __restrict__ refpts, const float* __restrict__ b_off,
    const float* __restrict__ b_attn, float* __restrict__ locbuf,
    float* __restrict__ awbuf) {
  __shared__ unsigned short ldsB[128 * 256];  // exactly 64 KB
  const int tid = threadIdx.x, lane = tid & 63, w = tid >> 6;
  const int wm = w >> 1, wn = w & 1;
  floatx4 acc[4][4];
  const floatx4 zero = {0.f, 0.f, 0.f, 0.f};
#pragma unroll
  for (int i2 = 0; i2 < 4; i2++)
#pragma unroll
    for (int j = 0; j < 4; j++) acc[i2][j] = zero;
  const int quad = lane >> 4, cl = lane & 15;

  if (blockIdx.x < 832) {
    const int chunk = blockIdx.x >> 4, i = blockIdx.x & 15;
    const int m0 = (chunk * 8 + (i & 7)) * 128;
    const int n0 = (i >> 3) * 128;
    loadB_tile(Wt_val, 256, n0, ldsB, tid);
    __syncthreads();
    gemm_bres_f32A(value, MV, m0, ldsB, wm, wn, lane, acc);
#pragma unroll
    for (int mt = 0; mt < 4; ++mt) {
#pragma unroll
      for (int r = 0; r < 4; ++r) {
        const int row = m0 + wm * 64 + mt * 16 + quad * 4 + r;
        if (row < MV) {
          const int b = row / NV, n = row - b * NV;
#pragma unroll
          for (int nt = 0; nt < 4; ++nt) {
            const int c = n0 + wn * 64 + nt * 16 + cl;
            const int h = c >> 5, d = c & 31;
            vbh[(((size_t)(b * NH + h)) * NV + n) * HD + d] =
                bf16bits(acc[mt][nt][r] + b_val[c]);
          }
        }
      }
    }
  } else {
    const int bid = blockIdx.x - 832;
    const int chunk = bid / 24, i = bid % 24;
    const int m_idx = chunk * 8 + (i & 7);
    if (m_idx >= 188) return;
    const int m0 = m_idx * 128;
    const int n0 = (i >> 3) * 128;
    loadB_tile(Wt_qcat, 384, n0, ldsB, tid);
    __syncthreads();
    gemm_bres_f32A(query, MQ, m0, ldsB, wm, wn, lane, acc);
    if (n0 < 256) {  // offset region
#pragma unroll
      for (int mt = 0; mt < 4; ++mt) {
#pragma unroll
        for (int r = 0; r < 4; ++r) {
          const int row = m0 + wm * 64 + mt * 16 + quad * 4 + r;
          if (row < MQ) {
#pragma unroll
            for (int nt = 0; nt < 4; ++nt) {
              const int c = n0 + wn * 64 + nt * 16 + cl;
              const int xy = c & 1, l = (c >> 3) & 3;
              const float dim = LVL_DIM[l];
              const float ref = refpts[(size_t)row * 8 + l * 2 + xy];
              locbuf[(size_t)row * 256 + c] =
                  ref * dim + acc[mt][nt][r] + b_off[c] - 0.5f;
            }
          }
        }
      }
    } else {  // attn region: softmax over 16 consecutive cols
#pragma unroll
      for (int mt = 0; mt < 4; ++mt) {
#pragma unroll
        for (int r = 0; r < 4; ++r) {
          const int row = m0 + wm * 64 + mt * 16 + quad * 4 + r;
          if (row < MQ) {
#pragma unroll
            for (int nt = 0; nt < 4; ++nt) {
              const int ca = wn * 64 + nt * 16 + cl;
              float v = acc[mt][nt][r] + b_attn[ca];
              float m = v;
              m = fmaxf(m, __shfl_xor(m, 1));
              m = fmaxf(m, __shfl_xor(m, 2));
              m = fmaxf(m, __shfl_xor(m, 4));
              m = fmaxf(m, __shfl_xor(m, 8));
              float e = __expf(v - m);
              float s = e;
              s += __shfl_xor(s, 1);
              s += __shfl_xor(s, 2);
              s += __shfl_xor(s, 4);
              s += __shfl_xor(s, 8);
              awbuf[(size_t)row * 128 + ca] = e / s;
            }
          }
        }
      }
    }
  }
}

// ---------------------------------------------------------------------------
// K3: bilinear sampling. Each wave: 2 rows of one (b,h) slice;
// 16 sample-groups x 4 lanes, lane owns 8 dims. Reduce-scatter finish.
// XCD-pinned via blockIdx&7.
// ---------------------------------------------------------------------------
__global__ __launch_bounds__(256, 4) void sample_kernel(
    const unsigned short* __restrict__ vbh, const float* __restrict__ locbuf,
    const float* __restrict__ awbuf, unsigned short* __restrict__ sampledb) {
  const int blk = blockIdx.x;
  const int t = blk >> 3;           // [0, 3000)
  const int quarter = t / 750;
  const int j = t - quarter * 750;  // [0, 750)
  const int slice = (blk & 7) * 4 + quarter;  // b*8 + h
  const int h = slice & 7;
  const int w = threadIdx.x >> 6;
  const int lane = threadIdx.x & 63;
  const int r0 = (slice >> 3) * NQ + j * 8 + w * 2;  // rows r0, r0+1
  const int g = lane >> 2;  // sample 0..15: l = g>>2, p = g&3
  const int d8 = lane & 3;  // dim octet
  const int l = g >> 2;

  const int W_ = (l < 2) ? ((l == 0) ? 100 : 50) : ((l == 2) ? 25 : 13);
  const int START = (l < 2) ? ((l == 0) ? 0 : 10000) : ((l == 2) ? 12500 : 13125);
  const unsigned int* base =
      (const unsigned int*)vbh + ((size_t)slice * NV + START) * 16 + d8 * 4;

  float acc0[8], acc1[8];
#pragma unroll
  for (int rr = 0; rr < 2; ++rr) {
    const int row = r0 + rr;
    float* a = rr ? acc1 : acc0;
    const float2 xy =
        *(const float2*)(locbuf + (size_t)row * 256 + h * 32 + g * 2);
    const float wgt = awbuf[(size_t)row * 128 + h * 16 + g];

    const float fx = floorf(xy.x), fy = floorf(xy.y);
    const int x0 = (int)fx, y0 = (int)fy;
    const float wx1 = xy.x - fx, wy1 = xy.y - fy;
    const float wx0 = 1.f - wx1, wy0 = 1.f - wy1;
    const int x0c = min(max(x0, 0), W_ - 1), x1c = min(max(x0 + 1, 0), W_ - 1);
    const int y0c = min(max(y0, 0), W_ - 1), y1c = min(max(y0 + 1, 0), W_ - 1);
    const float mx0 = ((unsigned)x0 < (unsigned)W_) ? wx0 : 0.f;
    const float mx1 = ((unsigned)(x0 + 1) < (unsigned)W_) ? wx1 : 0.f;
    const float my0 = ((unsigned)y0 < (unsigned)W_) ? wy0 : 0.f;
    const float my1 = ((unsigned)(y0 + 1) < (unsigned)W_) ? wy1 : 0.f;
    const float wy0w = wgt * my0, wy1w = wgt * my1;
    const float w00 = wy0w * mx0, w01 = wy0w * mx1;
    const float w10 = wy1w * mx0, w11 = wy1w * mx1;

    const int rb0 = y0c * W_, rb1 = y1c * W_;
    const uint4 u00 = *(const uint4*)(base + (size_t)(rb0 + x0c) * 16);
    const uint4 u01 = *(const uint4*)(base + (size_t)(rb0 + x1c) * 16);
    const uint4 u10 = *(const uint4*)(base + (size_t)(rb1 + x0c) * 16);
    const uint4 u11 = *(const uint4*)(base + (size_t)(rb1 + x1c) * 16);
    const unsigned int* p00 = &u00.x;
    const unsigned int* p01 = &u01.x;
    const unsigned int* p10 = &u10.x;
    const unsigned int* p11 = &u11.x;
#pragma unroll
    for (int k = 0; k < 4; ++k) {
      a[2 * k] = w00 * bflo(p00[k]) + w01 * bflo(p01[k]) + w10 * bflo(p10[k]) +
                 w11 * bflo(p11[k]);
      a[2 * k + 1] = w00 * bfhi(p00[k]) + w01 * bfhi(p01[k]) +
                     w10 * bfhi(p10[k]) + w11 * bfhi(p11[k]);
    }
  }

  const bool b0 = (lane >> 2) & 1;
  const bool b1 = (lane >> 3) & 1;
  const bool b2 = (lane >> 4) & 1;
#pragma unroll
  for (int rr = 0; rr < 2; ++rr) {
    float* v = rr ? acc1 : acc0;
#pragma unroll
    for (int jj = 0; jj < 4; ++jj) {
      float lo = v[jj], hi = v[jj + 4];
      float recv = __shfl_xor(b0 ? lo : hi, 4);
      v[jj] = (b0 ? hi : lo) + recv;
    }
#pragma unroll
    for (int jj = 0; jj < 2; ++jj) {
      float lo = v[jj], hi = v[jj + 2];
      float recv = __shfl_xor(b1 ? lo : hi, 8);
      v[jj] = (b1 ? hi : lo) + recv;
    }
    {
      float lo = v[0], hi = v[1];
      float recv = __shfl_xor(b2 ? lo : hi, 16);
      v[0] = (b2 ? hi : lo) + recv;
    }
    v[0] += __shfl_xor(v[0], 32);
  }

  const int dim = d8 * 8 + (b0 ? 4 : 0) + (b1 ? 2 : 0) + (b2 ? 1 : 0);
  const int row = (lane < 32) ? r0 : (r0 + 1);
  const float val = (lane < 32) ? acc0[0] : acc1[0];
  sampledb[(size_t)row * EMB + h * 32 + dim] = bf16bits(val);
}

// ---------------------------------------------------------------------------
// K4: out = sampled @ W_out + b_out + query (residual fused).
// ---------------------------------------------------------------------------
__global__ __launch_bounds__(256, 2) void oproj_kernel(
    const unsigned short* __restrict__ sampledb,
    const unsigned short* __restrict__ Wt, const float* __restrict__ b_out,
    const float* __restrict__ query, float* __restrict__ out) {
  __shared__ unsigned short ldsB[128 * 256];
  const int tid = threadIdx.x, lane = tid & 63, w = tid >> 6;
  const int wm = w >> 1, wn = w & 1;
  const int chunk = blockIdx.x >> 4, i = blockIdx.x & 15;
  const int m_idx = chunk * 8 + (i & 7);
  if (m_idx >= 188) return;
  const int m0 = m_idx * 128;
  const int n0 = (i >> 3) * 128;
  floatx4 acc[4][4];
  const floatx4 zero = {0.f, 0.f, 0.f, 0.f};
#pragma unroll
  for (int i2 = 0; i2 < 4; i2++)
#pragma unroll
    for (int j = 0; j < 4; j++) acc[i2][j] = zero;

  loadB_tile(Wt, 256, n0, ldsB, tid);
  __syncthreads();
  gemm_bres_bf16A(sampledb, MQ, m0, ldsB, wm, wn, lane, acc);

  const int quad = lane >> 4, cl = lane & 15;
#pragma unroll
  for (int mt = 0; mt < 4; ++mt) {
#pragma unroll
    for (int r = 0; r < 4; ++r) {
      const int row = m0 + wm * 64 + mt * 16 + quad * 4 + r;
      if (row < MQ) {
#pragma unroll
        for (int nt = 0; nt < 4; ++nt) {
          const int c = n0 + wn * 64 + nt * 16 + cl;
          out[(size_t)row * EMB + c] =
              acc[mt][nt][r] + b_out[c] + query[(size_t)row * EMB + c];
        }
      }
    }
  }
}

// ---------------------------------------------------------------------------
extern "C" void kernel_launch(void* const* d_in, const int* in_sizes, int n_in,
                              void* d_out, int out_size, void* d_ws,
                              size_t ws_size, hipStream_t stream) {
  const float* query  = (const float*)d_in[0];
  const float* value  = (const float*)d_in[1];
  const float* refpts = (const float*)d_in[2];
  const float* W_off  = (const float*)d_in[3];
  const float* b_off  = (const float*)d_in[4];
  const float* W_attn = (const float*)d_in[5];
  const float* b_attn = (const float*)d_in[6];
  const float* W_val  = (const float*)d_in[7];
  const float* b_val  = (const float*)d_in[8];
  const float* W_out  = (const float*)d_in[9];
  const float* b_out  = (const float*)d_in[10];
  float* out = (float*)d_out;

  char* ws = (char*)d_ws;
  unsigned short* vbh = (unsigned short*)ws;                   // 27,226,112 B
  float* locbuf = (float*)(ws + 27226112);                     // 24,576,000 B
  float* awbuf = (float*)(ws + 51802112);                      // 12,288,000 B
  unsigned short* sampledb = (unsigned short*)(ws + 64090112); // 12,288,000 B
  unsigned short* Wt_val = (unsigned short*)(ws + 76378112);   //    131,072 B
  unsigned short* Wt_qcat = (unsigned short*)(ws + 76509184);  //    196,608 B
  unsigned short* Wt_out = (unsigned short*)(ws + 76705792);   //    131,072 B

  wtrans_kernel<<<896, 256, 0, stream>>>(W_val, W_off, W_attn, W_out, Wt_val,
                                         Wt_qcat, Wt_out);
  vqproj_kernel<<<1408, 256, 0, stream>>>(value, Wt_val, b_val, vbh, query,
                                          Wt_qcat, refpts, b_off, b_attn,
                                          locbuf, awbuf);
  sample_kernel<<<24000, 256, 0, stream>>>(vbh, locbuf, awbuf, sampledb);
  oproj_kernel<<<384, 256, 0, stream>>>(sampledb, Wt_out, b_out, query, out);
}